// Round 9
// baseline (616.814 us; speedup 1.0000x reference)
//
#include <hip/hip_runtime.h>
#include <math.h>

typedef __attribute__((ext_vector_type(8))) short short8;
typedef __attribute__((ext_vector_type(4))) float f32x4;

__device__ __forceinline__ float b2f(short s) {
    unsigned u = ((unsigned)(unsigned short)s) << 16;
    return __builtin_bit_cast(float, u);
}
__device__ __forceinline__ short f2b(float f) {
    unsigned u = __builtin_bit_cast(unsigned, f);
    u += 0x7FFFu + ((u >> 16) & 1u);
    return (short)(u >> 16);
}

// ---- fused prep: 4 weight transposes (fp32->bf16) + bias C-frag precompute + gid ----
// segment boundaries are all multiples of 256 ->每block uniform branch
__global__ void prep_kernel(
    const float* __restrict__ qkv_w, const float* __restrict__ proj_w,
    const float* __restrict__ fc1_w, const float* __restrict__ fc2_w,
    const float* __restrict__ btab,
    short* __restrict__ wt_qkv, short* __restrict__ wt_proj,
    short* __restrict__ wt_fc1, short* __restrict__ wt_fc2,
    float* __restrict__ btf, unsigned char* __restrict__ gid)
{
    int idx = blockIdx.x * 256 + threadIdx.x;
    if (idx < 442368) {                      // qkv^T: N=1152, K=384
        int n = idx / 384, k = idx - n * 384;
        wt_qkv[idx] = f2b(qkv_w[(size_t)k * 1152 + n]);
        return;
    }
    idx -= 442368;
    if (idx < 147456) {                      // proj^T: 384x384
        int n = idx / 384, k = idx - n * 384;
        wt_proj[idx] = f2b(proj_w[(size_t)k * 384 + n]);
        return;
    }
    idx -= 147456;
    if (idx < 589824) {                      // fc1^T: N=1536, K=384
        int n = idx / 384, k = idx - n * 384;
        wt_fc1[idx] = f2b(fc1_w[(size_t)k * 1536 + n]);
        return;
    }
    idx -= 589824;
    if (idx < 589824) {                      // fc2^T: N=384, K=1536
        int n = idx / 1536, k = idx - n * 1536;
        wt_fc2[idx] = f2b(fc2_w[(size_t)k * 384 + n]);
        return;
    }
    idx -= 589824;
    if (idx < 371712) {                      // bias in C-frag layout btf[12][22][22][64][4]
        int lane = idx & 63, rem = idx >> 6;
        int nb = rem % 22; rem /= 22;
        int rt = rem % 22; int head = rem / 22;
        int j = nb * 16 + (lane & 15);
        int ibase = rt * 16 + (lane >> 4) * 4;
        f32x4 out;
        #pragma unroll
        for (int r = 0; r < 4; r++) {
            int i = ibase + r;
            float v;
            if (j >= 344) v = -1e30f;
            else if (i >= 344 || i == 0 || j == 0) v = 0.f;
            else {
                int ti = i - 1, tj = j - 1;
                int ai = ti / 49, bi = (ti % 49) / 7, ci = ti % 7;
                int aj = tj / 49, bj = (tj % 49) / 7, cj = tj % 7;
                int id3 = (ai - aj + 6) * 20 + (bi - bj + 6) * 13 + (ci - cj + 6);
                v = btab[id3 * 12 + head];
            }
            out[r] = v;
        }
        *(f32x4*)&btf[(size_t)idx * 4] = out;
        return;
    }
    idx -= 371712;
    if (idx < 22528) {                       // gid[64][352]
        int w = idx / 352, n = idx - w * 352;
        unsigned char g = 0;
        if (n >= 1 && n < 344) {
            int t = n - 1;
            int a = t / 49, bb = (t % 49) / 7, cc = t % 7;
            int hw = w >> 3, ww = w & 7;
            int h = hw * 7 + bb, wd = ww * 7 + cc;
            int gs = (a < 4) ? 1 : 2;
            int gh = (h < 49) ? 0 : ((h < 53) ? 1 : 2);
            int gw = (wd < 49) ? 0 : ((wd < 53) ? 1 : 2);
            g = (unsigned char)(gs * 9 + gh * 3 + gw);
        }
        gid[idx] = g;
    }
}

// ---------------- LN1 + roll(-3) + window partition + gt concat ----------------
__global__ __launch_bounds__(256) void ln1_window(
    const float* __restrict__ x, const float* __restrict__ gt,
    const float* __restrict__ g, const float* __restrict__ b,
    short* __restrict__ xc)
{
    int wid = threadIdx.x >> 6, lane = threadIdx.x & 63;
    int r = blockIdx.x * 4 + wid;
    int w = r / 344, n = r - w * 344;
    if (n == 0) {
        #pragma unroll
        for (int i = 0; i < 6; i++) {
            int c = lane + i * 64;
            xc[(size_t)r * 384 + c] = f2b(gt[(size_t)w * 384 + c]);
        }
        return;
    }
    int t = n - 1;
    int a = t / 49, rm = t - a * 49, bb = rm / 7, cc = rm - bb * 7;
    int hw = w >> 3, ww = w & 7;
    int s = (a < 4) ? a + 3 : a - 4;
    int h = hw * 7 + bb + 3; if (h >= 56) h -= 56;
    int wd = ww * 7 + cc + 3; if (wd >= 56) wd -= 56;
    const float* row = x + (size_t)((s * 56 + h) * 56 + wd) * 384;
    float v[6]; float sum = 0.f;
    #pragma unroll
    for (int i = 0; i < 6; i++) { v[i] = row[lane + i * 64]; sum += v[i]; }
    #pragma unroll
    for (int off = 32; off >= 1; off >>= 1) sum += __shfl_xor(sum, off);
    float mu = sum * (1.0f / 384.0f);
    float vs = 0.f;
    #pragma unroll
    for (int i = 0; i < 6; i++) { float d = v[i] - mu; vs += d * d; }
    #pragma unroll
    for (int off = 32; off >= 1; off >>= 1) vs += __shfl_xor(vs, off);
    float rstd = rsqrtf(vs * (1.0f / 384.0f) + 1e-5f);
    #pragma unroll
    for (int i = 0; i < 6; i++) {
        int c = lane + i * 64;
        float o = (v[i] - mu) * rstd * g[c] + b[c];
        xc[(size_t)r * 384 + c] = f2b(o);
    }
}

// ---------------- LN2 over fp32 x_new, token-major, out bf16 ----------------
__global__ __launch_bounds__(256) void ln2_kernel(
    const float* __restrict__ xn, const float* __restrict__ g,
    const float* __restrict__ b, short* __restrict__ out)
{
    int wid = threadIdx.x >> 6, lane = threadIdx.x & 63;
    int r = blockIdx.x * 4 + wid;
    const float* row = xn + (size_t)r * 384;
    float v[6]; float sum = 0.f;
    #pragma unroll
    for (int i = 0; i < 6; i++) { v[i] = row[lane + i * 64]; sum += v[i]; }
    #pragma unroll
    for (int off = 32; off >= 1; off >>= 1) sum += __shfl_xor(sum, off);
    float mu = sum * (1.0f / 384.0f);
    float vs = 0.f;
    #pragma unroll
    for (int i = 0; i < 6; i++) { float d = v[i] - mu; vs += d * d; }
    #pragma unroll
    for (int off = 32; off >= 1; off >>= 1) vs += __shfl_xor(vs, off);
    float rstd = rsqrtf(vs * (1.0f / 384.0f) + 1e-5f);
    #pragma unroll
    for (int i = 0; i < 6; i++) {
        int c = lane + i * 64;
        float o = (v[i] - mu) * rstd * g[c] + b[c];
        out[(size_t)r * 384 + c] = f2b(o);
    }
}

// ---- 128x128 bf16 MFMA GEMM, BK=64, register-prefetch pipeline + XOR-swizzled LDS ----
// LDS layout identical to verified round-8 swizzle (0 conflicts): row r slot cs holds
// global chunk cs^(r&7); writes are contiguous (lane*16B per wave region).
// Raw s_barrier (no vmcnt drain) keeps prefetch loads in flight across compute.
template<int EPI, bool QS>
__global__ __launch_bounds__(256, 4) void gemm128(
    const short* __restrict__ A, const short* __restrict__ BT,
    const float* __restrict__ bias, void* __restrict__ Out,
    const void* __restrict__ P0, void* __restrict__ P1,
    int M, int N, int K)
{
    __shared__ short As[128 * 64];
    __shared__ short Bs[128 * 64];
    const int m0 = blockIdx.y * 128, n0 = blockIdx.x * 128;
    const int tid = threadIdx.x;
    const int wid = tid >> 6, lane = tid & 63;
    const int wm = wid >> 1, wn = wid & 1;
    const int l15 = lane & 15, quad = lane >> 4;

    f32x4 acc[4][4];
    #pragma unroll
    for (int i = 0; i < 4; i++)
        #pragma unroll
        for (int j = 0; j < 4; j++) acc[i][j] = (f32x4){0.f, 0.f, 0.f, 0.f};

    const int trow = tid >> 3;                 // 0..31
    const int cs = tid & 7;
    const int gc = cs ^ (trow & 7);            // global 16B-chunk for slot cs
    const short* Ag[4]; const short* Bg[4];
    #pragma unroll
    for (int j = 0; j < 4; j++) {
        int ar = m0 + j * 32 + trow; if (ar >= M) ar = M - 1;
        Ag[j] = A + (size_t)ar * K + gc * 8;
        Bg[j] = BT + (size_t)(n0 + j * 32 + trow) * K + gc * 8;
    }
    // LDS write ptrs: wave-region base + lane*16B == row (j*32+trow), slot cs
    short* AsT[4]; short* BsT[4];
    #pragma unroll
    for (int j = 0; j < 4; j++) {
        AsT[j] = &As[(j * 32 + wid * 8) * 64 + lane * 8];
        BsT[j] = &Bs[(j * 32 + wid * 8) * 64 + lane * 8];
    }
    int arow[4], brow[4];
    #pragma unroll
    for (int mt = 0; mt < 4; mt++) arow[mt] = wm * 64 + mt * 16 + l15;
    #pragma unroll
    for (int nt = 0; nt < 4; nt++) brow[nt] = wn * 64 + nt * 16 + l15;

    short8 ra[4], rb[4];
    #pragma unroll
    for (int j = 0; j < 4; j++) { ra[j] = *(const short8*)Ag[j]; rb[j] = *(const short8*)Bg[j]; }

    for (int ks = 0; ks < K; ks += 64) {
        // barrier #1: all waves' ds_reads of prev tile already consumed by MFMA
        asm volatile("s_barrier" ::: "memory");
        #pragma unroll
        for (int j = 0; j < 4; j++) *(short8*)AsT[j] = ra[j];
        #pragma unroll
        for (int j = 0; j < 4; j++) *(short8*)BsT[j] = rb[j];
        if (ks + 64 < K) {
            #pragma unroll
            for (int j = 0; j < 4; j++) {
                ra[j] = *(const short8*)(Ag[j] + ks + 64);
                rb[j] = *(const short8*)(Bg[j] + ks + 64);
            }
        }
        // barrier #2: drain own ds_writes, then sync (prefetch loads stay in flight)
        asm volatile("s_waitcnt lgkmcnt(0)\n\ts_barrier" ::: "memory");
        #pragma unroll
        for (int ko = 0; ko < 2; ko++) {
            short8 af[4], bf[4];
            #pragma unroll
            for (int mt = 0; mt < 4; mt++)
                af[mt] = *(const short8*)&As[arow[mt] * 64
                         + (((ko * 4 + quad) ^ (l15 & 7)) * 8)];
            #pragma unroll
            for (int nt = 0; nt < 4; nt++)
                bf[nt] = *(const short8*)&Bs[brow[nt] * 64
                         + (((ko * 4 + quad) ^ (l15 & 7)) * 8)];
            #pragma unroll
            for (int mt = 0; mt < 4; mt++)
                #pragma unroll
                for (int nt = 0; nt < 4; nt++)
                    acc[mt][nt] = __builtin_amdgcn_mfma_f32_16x16x32_bf16(
                        af[mt], bf[nt], acc[mt][nt], 0, 0, 0);
        }
    }

    #pragma unroll
    for (int mt = 0; mt < 4; mt++) {
        #pragma unroll
        for (int nt = 0; nt < 4; nt++) {
            #pragma unroll
            for (int r = 0; r < 4; r++) {
                int row = m0 + wm * 64 + mt * 16 + quad * 4 + r;
                int col = n0 + wn * 64 + nt * 16 + l15;
                if (row >= M) continue;
                float v = acc[mt][nt][r] + bias[col];
                if (EPI == 0) {
                    if (QS && col < 384) v *= 0.17677669529663687f;
                    ((short*)Out)[(size_t)row * N + col] = f2b(v);
                } else if (EPI == 1) {
                    // tanh-form GELU: v*sigmoid(2*0.79788456*(v+0.044715 v^3))
                    float z = 1.5957691216057308f * (v + 0.044715f * v * v * v);
                    v = v / (1.0f + __expf(-z));
                    ((short*)Out)[(size_t)row * N + col] = f2b(v);
                } else if (EPI == 2) {
                    int w = row / 344, n = row - w * 344;
                    if (n == 0) {
                        ((float*)P1)[(size_t)w * 384 + col] = v;
                    } else {
                        int t = n - 1;
                        int a = t / 49, rm = t - a * 49;
                        int bb = rm / 7, cc = rm - bb * 7;
                        int hw = w >> 3, ww = w & 7;
                        int s = (a < 4) ? a + 3 : a - 4;
                        int h = hw * 7 + bb + 3; if (h >= 56) h -= 56;
                        int wd = ww * 7 + cc + 3; if (wd >= 56) wd -= 56;
                        size_t td = (size_t)((s * 56 + h) * 56 + wd) * 384 + col;
                        ((float*)Out)[td] = v + ((const float*)P0)[td];
                    }
                } else {  // EPI 3
                    v += ((const float*)P0)[(size_t)row * N + col];
                    ((float*)Out)[(size_t)row * N + col] = v;
                }
            }
        }
    }
}

// -------- fused windowed attention: K+V in LDS, no-max softmax (scores bounded) --------
__global__ __launch_bounds__(256) void attn_kernel(
    const short* __restrict__ qkv, const float* __restrict__ btf,
    const unsigned char* __restrict__ gid, short* __restrict__ attn_out)
{
    __shared__ short KT[352 * 40];
    __shared__ short VT[32 * 360];
    __shared__ short Pbuf[4 * 16 * 40];
    __shared__ unsigned char Gs[352];
    const int blk = blockIdx.x;
    const int half = blk & 1, wh = blk >> 1;
    const int w = wh / 12, head = wh - w * 12;
    const int tid = threadIdx.x;
    const int wid = tid >> 6, lane = tid & 63;
    const int l15 = lane & 15, quad = lane >> 4;
    const size_t base = (size_t)w * 344 * 1152 + head * 32;

    for (int c = tid; c < 352 * 4; c += 256) {
        int row = c >> 2, off = (c & 3) * 8;
        short8 v8 = (short8){0,0,0,0,0,0,0,0};
        if (row < 344) v8 = *(const short8*)&qkv[base + 384 + (size_t)row * 1152 + off];
        *(short8*)&KT[row * 40 + off] = v8;
    }
    for (int e = tid; e < 344 * 32; e += 256) {
        int key = e >> 5, dd = e & 31;
        VT[dd * 360 + key] = qkv[base + 768 + (size_t)key * 1152 + dd];
    }
    for (int e = tid; e < 16 * 32; e += 256) {
        int key = 344 + (e >> 5), dd = e & 31;
        VT[dd * 360 + key] = 0;
    }
    for (int e = tid; e < 352; e += 256) Gs[e] = gid[w * 352 + e];
    __syncthreads();

    const float* bh = btf + (size_t)head * (22 * 22 * 256);
    short* Pw = &Pbuf[wid * 640];

    for (int rtl = wid; rtl < 11; rtl += 4) {
        int rt = half * 11 + rtl;
        int mbase = rt * 16;
        int qr = mbase + l15; if (qr > 343) qr = 343;
        short8 af = *(const short8*)&qkv[base + (size_t)qr * 1152 + quad * 8];

        int rg[4]; bool ip[4];
        #pragma unroll
        for (int r = 0; r < 4; r++) {
            int i = mbase + quad * 4 + r;
            rg[r] = Gs[i];
            ip[r] = (i > 0);
        }

        f32x4 o0 = {0.f, 0.f, 0.f, 0.f}, o1 = {0.f, 0.f, 0.f, 0.f};
        float l[4] = {0.f, 0.f, 0.f, 0.f};

        #pragma unroll
        for (int kk = 0; kk < 11; kk++) {
            int nb0 = kk * 2, nb1 = kk * 2 + 1;
            f32x4 b0 = *(const f32x4*)&bh[((size_t)(rt * 22 + nb0) * 64 + lane) * 4];
            f32x4 b1 = *(const f32x4*)&bh[((size_t)(rt * 22 + nb1) * 64 + lane) * 4];
            short8 k0 = *(const short8*)&KT[(nb0 * 16 + l15) * 40 + quad * 8];
            short8 k1 = *(const short8*)&KT[(nb1 * 16 + l15) * 40 + quad * 8];
            f32x4 s0 = __builtin_amdgcn_mfma_f32_16x16x32_bf16(af, k0, b0, 0, 0, 0);
            f32x4 s1 = __builtin_amdgcn_mfma_f32_16x16x32_bf16(af, k1, b1, 0, 0, 0);

            int j0 = nb0 * 16 + l15;
            int cg0 = Gs[j0], cg1 = Gs[j0 + 16];
            bool jp0 = (j0 > 0);
            #pragma unroll
            for (int r = 0; r < 4; r++) {
                float s0r = s0[r], s1r = s1[r];
                if (jp0 && ip[r] && rg[r] != cg0) s0r -= 100.0f;
                if (ip[r] && rg[r] != cg1) s1r -= 100.0f;
                float p0 = __expf(s0r);
                float p1 = __expf(s1r);
                l[r] += p0 + p1;
                Pw[(quad * 4 + r) * 40 + l15] = f2b(p0);
                Pw[(quad * 4 + r) * 40 + 16 + l15] = f2b(p1);
            }
            short8 pa = *(const short8*)&Pw[l15 * 40 + quad * 8];
            short8 v0 = *(const short8*)&VT[l15 * 360 + kk * 32 + quad * 8];
            short8 v1 = *(const short8*)&VT[(16 + l15) * 360 + kk * 32 + quad * 8];
            o0 = __builtin_amdgcn_mfma_f32_16x16x32_bf16(pa, v0, o0, 0, 0, 0);
            o1 = __builtin_amdgcn_mfma_f32_16x16x32_bf16(pa, v1, o1, 0, 0, 0);
        }

        #pragma unroll
        for (int r = 0; r < 4; r++) {
            l[r] += __shfl_xor(l[r], 1);
            l[r] += __shfl_xor(l[r], 2);
            l[r] += __shfl_xor(l[r], 4);
            l[r] += __shfl_xor(l[r], 8);
        }
        #pragma unroll
        for (int r = 0; r < 4; r++) {
            int row = mbase + quad * 4 + r;
            if (row < 344) {
                float inv = 1.0f / l[r];
                size_t ob = ((size_t)w * 344 + row) * 384 + head * 32;
                attn_out[ob + l15] = f2b(o0[r] * inv);
                attn_out[ob + 16 + l15] = f2b(o1[r] * inv);
            }
        }
    }
}

extern "C" void kernel_launch(void* const* d_in, const int* in_sizes, int n_in,
                              void* d_out, int out_size, void* d_ws, size_t ws_size,
                              hipStream_t stream)
{
    const float* x      = (const float*)d_in[0];
    const float* gt     = (const float*)d_in[1];
    const float* n1g    = (const float*)d_in[2];
    const float* n1b    = (const float*)d_in[3];
    const float* qkv_w  = (const float*)d_in[4];
    const float* qkv_b  = (const float*)d_in[5];
    const float* btab   = (const float*)d_in[6];
    const float* proj_w = (const float*)d_in[7];
    const float* proj_b = (const float*)d_in[8];
    const float* n2g    = (const float*)d_in[9];
    const float* n2b    = (const float*)d_in[10];
    const float* fc1_w  = (const float*)d_in[11];
    const float* fc1_b  = (const float*)d_in[12];
    const float* fc2_w  = (const float*)d_in[13];
    const float* fc2_b  = (const float*)d_in[14];

    char* ws = (char*)d_ws;
    short* wt_qkv  = (short*)(ws + 0);          //  1152x384 bf16
    short* wt_proj = (short*)(ws + 884736);     //   384x384 bf16
    short* wt_fc1  = (short*)(ws + 1179648);    //  1536x384 bf16
    short* wt_fc2  = (short*)(ws + 2359296);    //   384x1536 bf16
    short* xc      = (short*)(ws + 3538944);    // 22016x384 bf16
    short* qkvb    = (short*)(ws + 20447232);   // 22016x1152 bf16
    short* attn_o  = xc;                        // reuse (xc dead after qkv GEMM)
    short* h1      = (short*)(ws + 3538944);    // 21952x1536 bf16 (reuse xc region)
    float* xnew    = (float*)(ws + 71172096);   // 21952x384 fp32
    float* btf     = (float*)(ws + 71172096);   // 12x22x22x64x4 fp32 (dead before xnew)
    unsigned char* gidb = (unsigned char*)(ws + 77119488);  // 64x352 u8
    short* xnorm   = (short*)(ws + 104890368);  // 21952x384 bf16

    float* outx  = (float*)d_out;
    float* outgt = outx + (size_t)21952 * 384;

    prep_kernel<<<dim3(8452), 256, 0, stream>>>(qkv_w, proj_w, fc1_w, fc2_w, btab,
                                                wt_qkv, wt_proj, wt_fc1, wt_fc2,
                                                btf, gidb);

    ln1_window<<<dim3(5504), 256, 0, stream>>>(x, gt, n1g, n1b, xc);

    gemm128<0, true><<<dim3(9, 172), 256, 0, stream>>>(xc, wt_qkv, qkv_b, qkvb,
                                                       nullptr, nullptr, 22016, 1152, 384);

    attn_kernel<<<dim3(1536), 256, 0, stream>>>(qkvb, btf, gidb, attn_o);

    gemm128<2, false><<<dim3(3, 172), 256, 0, stream>>>(attn_o, wt_proj, proj_b, xnew,
                                                        x, outgt, 22016, 384, 384);

    ln2_kernel<<<dim3(5488), 256, 0, stream>>>(xnew, n2g, n2b, xnorm);

    gemm128<1, false><<<dim3(12, 172), 256, 0, stream>>>(xnorm, wt_fc1, fc1_b, h1,
                                                         nullptr, nullptr, 21952, 1536, 384);

    gemm128<3, false><<<dim3(3, 172), 256, 0, stream>>>(h1, wt_fc2, fc2_b, outx,
                                                        xnew, nullptr, 21952, 384, 1536);
}